// Round 9
// baseline (991.445 us; speedup 1.0000x reference)
//
#include <hip/hip_runtime.h>
#include <math.h>

#define BB 1024
#define TT 512

typedef __attribute__((ext_vector_type(8))) short  short8;
typedef __attribute__((ext_vector_type(4))) float  floatx4;

__device__ __forceinline__ float fast_rcp(float x){ return __builtin_amdgcn_rcpf(x); }
__device__ __forceinline__ float sigmoidf_(float x){ return fast_rcp(1.0f + __expf(-x)); }
__device__ __forceinline__ float tanhf_(float x){
    float t = __expf(2.0f * x);
    return 1.0f - 2.0f * fast_rcp(t + 1.0f);
}
// f32 -> bf16 bits, round-nearest-even
__device__ __forceinline__ short f2bf(float f){
    unsigned u = __builtin_bit_cast(unsigned, f);
    u += 0x7fffu + ((u >> 16) & 1u);
    return (short)(u >> 16);
}

// ---------------------------------------------------------------------------
// Layer 0 bidirectional GRU, MFMA-batched: 1 wave = 16 sequences of one dir.
// Per step: xg = mfma(x-tile zero-padded k=4), hg = mfma(h-tile k=32), 6 gate
// tiles each. D-layout: col=lane&15 (gate), row=quad*4+reg (batch) -> r/z/n
// for one (b,i) land in the SAME lane: gate math fully in-lane, no shuffles.
// h master stays f32 in registers; bf16 copy round-trips through LDS to form
// the next step's A-fragment (A[m=lane&15][k=quad*8+j]). Single wave -> no
// barriers. h1 output stored as bf16 (l1 quantizes to bf16 anyway).
// ---------------------------------------------------------------------------
__global__ __launch_bounds__(64, 1) void gru_l0(
    const float* __restrict__ x,      // (B,T,4) f32
    const float* __restrict__ w_ih,   // (2,96,4)
    const float* __restrict__ w_hh,   // (2,96,32)
    const float* __restrict__ b_ih,   // (2,96)
    const float* __restrict__ b_hh,   // (2,96)
    unsigned short* __restrict__ h1)  // (B,T,64) bf16
{
    const int bt  = blockIdx.x >> 1;
    const int d   = blockIdx.x & 1;
    const int b0  = bt * 16;
    const int L   = threadIdx.x;
    const int col = L & 15;      // gate-within-tile / A-row index
    const int quad= L >> 4;

    // B-fragments (weights, bf16). B[n=col][k=quad*8+j].
    short8 bhh[6], bih[6];
    #pragma unroll
    for (int gt = 0; gt < 6; ++gt){
        const int row = d*96 + gt*16 + col;
        short8 f;
        #pragma unroll
        for (int j = 0; j < 8; ++j) f[j] = f2bf(w_hh[(size_t)row*32 + quad*8 + j]);
        bhh[gt] = f;
        short8 fi = {0,0,0,0,0,0,0,0};
        if (quad == 0){
            #pragma unroll
            for (int j = 0; j < 4; ++j) fi[j] = f2bf(w_ih[(size_t)row*4 + j]);
        }
        bih[gt] = fi;
    }
    // per-lane bias scalars (2 i-halves each)
    float br[2], bz[2], bni[2], bhn[2];
    #pragma unroll
    for (int hf = 0; hf < 2; ++hf){
        const int gr = d*96 + hf*16 + col;
        br[hf]  = b_ih[gr]      + b_hh[gr];
        bz[hf]  = b_ih[gr + 32] + b_hh[gr + 32];
        bni[hf] = b_ih[gr + 64];
        bhn[hf] = b_hh[gr + 64];
    }

    __shared__ unsigned short hsh[16*40];   // bf16 h tile, row stride 40
    *(short8*)(&hsh[(L>>2)*40 + (L&3)*8]) = (short8){0,0,0,0,0,0,0,0};
    float hr[8];
    #pragma unroll
    for (int k = 0; k < 8; ++k) hr[k] = 0.0f;

    const size_t xrow = (size_t)(b0 + col) * TT;
    float4 xv = {0.f,0.f,0.f,0.f};
    if (quad == 0) xv = *(const float4*)(x + (xrow + (d ? TT-1 : 0))*4);

    const floatx4 z4 = {0.f,0.f,0.f,0.f};
    for (int t = 0; t < TT; ++t){
        const int tx = d ? (TT-1-t) : t;
        // A-fragments
        short8 ax = {0,0,0,0,0,0,0,0};
        if (quad == 0){ ax[0]=f2bf(xv.x); ax[1]=f2bf(xv.y); ax[2]=f2bf(xv.z); ax[3]=f2bf(xv.w); }
        const short8 ah = *(const short8*)(&hsh[col*40 + quad*8]);

        floatx4 xg[6], hg[6];
        #pragma unroll
        for (int gt = 0; gt < 6; ++gt)
            xg[gt] = __builtin_amdgcn_mfma_f32_16x16x32_bf16(ax, bih[gt], z4, 0, 0, 0);
        #pragma unroll
        for (int gt = 0; gt < 6; ++gt)
            hg[gt] = __builtin_amdgcn_mfma_f32_16x16x32_bf16(ah, bhh[gt], z4, 0, 0, 0);

        // prefetch next x row
        if (quad == 0 && t+1 < TT)
            xv = *(const float4*)(x + (xrow + (d ? TT-2-t : t+1))*4);

        #pragma unroll
        for (int hf = 0; hf < 2; ++hf){
            #pragma unroll
            for (int r4 = 0; r4 < 4; ++r4){
                const float rg = sigmoidf_(xg[hf][r4]   + hg[hf][r4]   + br[hf]);
                const float zg = sigmoidf_(xg[2+hf][r4] + hg[2+hf][r4] + bz[hf]);
                const float ng = tanhf_(xg[4+hf][r4] + bni[hf] + rg*(hg[4+hf][r4] + bhn[hf]));
                const int idx = hf*4 + r4;
                hr[idx] = ng + zg*(hr[idx] - ng);
                hsh[(quad*4+r4)*40 + hf*16 + col] = (unsigned short)f2bf(hr[idx]);
            }
        }
        // coalesced h1 store via the LDS tile (16B/lane)
        const short8 hv = *(const short8*)(&hsh[(L>>2)*40 + (L&3)*8]);
        *(short8*)(&h1[((size_t)(b0 + (L>>2))*TT + tx)*64 + d*32 + (L&3)*8]) = hv;
    }
}

// ---------------------------------------------------------------------------
// Layer 1: same structure, input width 64 -> xg = 2 k-tiles of MFMA reading
// bf16 h1 directly as A-fragments (no cvt). out2 stored f32 for attention.
// ---------------------------------------------------------------------------
__global__ __launch_bounds__(64, 1) void gru_l1(
    const unsigned short* __restrict__ h1,  // (B,T,64) bf16
    const float* __restrict__ w_ih,   // (2,96,64)
    const float* __restrict__ w_hh,   // (2,96,32)
    const float* __restrict__ b_ih,   // (2,96)
    const float* __restrict__ b_hh,   // (2,96)
    float* __restrict__ out2)         // (B,T,64) f32
{
    const int bt  = blockIdx.x >> 1;
    const int d   = blockIdx.x & 1;
    const int b0  = bt * 16;
    const int L   = threadIdx.x;
    const int col = L & 15;
    const int quad= L >> 4;

    short8 bhh[6], bi0[6], bi1[6];
    #pragma unroll
    for (int gt = 0; gt < 6; ++gt){
        const int row = d*96 + gt*16 + col;
        short8 f, g0, g1;
        #pragma unroll
        for (int j = 0; j < 8; ++j){
            f[j]  = f2bf(w_hh[(size_t)row*32 + quad*8 + j]);
            g0[j] = f2bf(w_ih[(size_t)row*64 +      quad*8 + j]);
            g1[j] = f2bf(w_ih[(size_t)row*64 + 32 + quad*8 + j]);
        }
        bhh[gt] = f; bi0[gt] = g0; bi1[gt] = g1;
    }
    float br[2], bz[2], bni[2], bhn[2];
    #pragma unroll
    for (int hf = 0; hf < 2; ++hf){
        const int gr = d*96 + hf*16 + col;
        br[hf]  = b_ih[gr]      + b_hh[gr];
        bz[hf]  = b_ih[gr + 32] + b_hh[gr + 32];
        bni[hf] = b_ih[gr + 64];
        bhn[hf] = b_hh[gr + 64];
    }

    __shared__ unsigned short hsh[16*40];
    *(short8*)(&hsh[(L>>2)*40 + (L&3)*8]) = (short8){0,0,0,0,0,0,0,0};
    float hr[8];
    #pragma unroll
    for (int k = 0; k < 8; ++k) hr[k] = 0.0f;

    const size_t arow = (size_t)(b0 + col) * TT;
    short8 a0, a1;
    {
        const int tx0 = d ? TT-1 : 0;
        a0 = *(const short8*)(&h1[(arow + tx0)*64 +      quad*8]);
        a1 = *(const short8*)(&h1[(arow + tx0)*64 + 32 + quad*8]);
    }

    const floatx4 z4 = {0.f,0.f,0.f,0.f};
    for (int t = 0; t < TT; ++t){
        const int tx = d ? (TT-1-t) : t;
        const short8 ah = *(const short8*)(&hsh[col*40 + quad*8]);

        floatx4 xg[6], hg[6];
        #pragma unroll
        for (int gt = 0; gt < 6; ++gt){
            floatx4 acc = __builtin_amdgcn_mfma_f32_16x16x32_bf16(a0, bi0[gt], z4, 0, 0, 0);
            xg[gt]      = __builtin_amdgcn_mfma_f32_16x16x32_bf16(a1, bi1[gt], acc, 0, 0, 0);
        }
        #pragma unroll
        for (int gt = 0; gt < 6; ++gt)
            hg[gt] = __builtin_amdgcn_mfma_f32_16x16x32_bf16(ah, bhh[gt], z4, 0, 0, 0);

        // prefetch next h1 row
        if (t+1 < TT){
            const int tx1 = d ? (TT-2-t) : (t+1);
            a0 = *(const short8*)(&h1[(arow + tx1)*64 +      quad*8]);
            a1 = *(const short8*)(&h1[(arow + tx1)*64 + 32 + quad*8]);
        }

        #pragma unroll
        for (int hf = 0; hf < 2; ++hf){
            #pragma unroll
            for (int r4 = 0; r4 < 4; ++r4){
                const float rg = sigmoidf_(xg[hf][r4]   + hg[hf][r4]   + br[hf]);
                const float zg = sigmoidf_(xg[2+hf][r4] + hg[2+hf][r4] + bz[hf]);
                const float ng = tanhf_(xg[4+hf][r4] + bni[hf] + rg*(hg[4+hf][r4] + bhn[hf]));
                const int idx = hf*4 + r4;
                hr[idx] = ng + zg*(hr[idx] - ng);
                hsh[(quad*4+r4)*40 + hf*16 + col] = (unsigned short)f2bf(hr[idx]);
                out2[((size_t)(b0 + quad*4 + r4)*TT + tx)*64 + d*32 + hf*16 + col] = hr[idx];
            }
        }
    }
}

// Attention pooling + FC + sigmoid. One block per batch element. (unchanged)
__global__ __launch_bounds__(256) void attn_fc(
    const float* __restrict__ out2,   // (B,T,64)
    const float* __restrict__ attn_w, // (64)
    const float* __restrict__ attn_b, // (1)
    const float* __restrict__ fc_w,   // (64)
    const float* __restrict__ fc_b,   // (1)
    float* __restrict__ out)          // (B,1)
{
    const int b    = blockIdx.x;
    const int tid  = threadIdx.x;
    const int wave = tid >> 6;
    const int lane = tid & 63;

    __shared__ float logit_sh[TT];
    __shared__ float red_sh[4];
    __shared__ float ctx_sh[4][64];

    const float aw = attn_w[lane];
    const float ab = attn_b[0];

    for (int t = wave; t < TT; t += 4) {
        float v = out2[((size_t)b*TT + t)*64 + lane] * aw;
        #pragma unroll
        for (int off = 32; off > 0; off >>= 1) v += __shfl_xor(v, off, 64);
        if (lane == 0) logit_sh[t] = v + ab;
    }
    __syncthreads();

    float m = -INFINITY;
    for (int t = tid; t < TT; t += 256) m = fmaxf(m, logit_sh[t]);
    #pragma unroll
    for (int off = 32; off > 0; off >>= 1) m = fmaxf(m, __shfl_xor(m, off, 64));
    if (lane == 0) red_sh[wave] = m;
    __syncthreads();
    m = fmaxf(fmaxf(red_sh[0], red_sh[1]), fmaxf(red_sh[2], red_sh[3]));
    __syncthreads();
    float s = 0.0f;
    for (int t = tid; t < TT; t += 256) {
        const float e = __expf(logit_sh[t] - m);
        logit_sh[t] = e;
        s += e;
    }
    #pragma unroll
    for (int off = 32; off > 0; off >>= 1) s += __shfl_xor(s, off, 64);
    if (lane == 0) red_sh[wave] = s;
    __syncthreads();
    s = red_sh[0] + red_sh[1] + red_sh[2] + red_sh[3];
    const float inv_s = 1.0f / s;

    float acc = 0.0f;
    for (int t = wave; t < TT; t += 4)
        acc += logit_sh[t] * out2[((size_t)b*TT + t)*64 + lane];
    ctx_sh[wave][lane] = acc;
    __syncthreads();
    if (wave == 0) {
        const float c = (ctx_sh[0][lane] + ctx_sh[1][lane] +
                         ctx_sh[2][lane] + ctx_sh[3][lane]) * inv_s;
        float v = c * fc_w[lane];
        #pragma unroll
        for (int off = 32; off > 0; off >>= 1) v += __shfl_xor(v, off, 64);
        if (lane == 0) out[b] = sigmoidf_(v + fc_b[0]);
    }
}

extern "C" void kernel_launch(void* const* d_in, const int* in_sizes, int n_in,
                              void* d_out, int out_size, void* d_ws, size_t ws_size,
                              hipStream_t stream) {
    (void)in_sizes; (void)n_in; (void)out_size; (void)ws_size;
    const float* x      = (const float*)d_in[0];
    const float* w_ih0  = (const float*)d_in[1];
    const float* w_hh0  = (const float*)d_in[2];
    const float* b_ih0  = (const float*)d_in[3];
    const float* b_hh0  = (const float*)d_in[4];
    const float* w_ih1  = (const float*)d_in[5];
    const float* w_hh1  = (const float*)d_in[6];
    const float* b_ih1  = (const float*)d_in[7];
    const float* b_hh1  = (const float*)d_in[8];
    const float* attn_w = (const float*)d_in[9];
    const float* attn_b = (const float*)d_in[10];
    const float* fc_w   = (const float*)d_in[11];
    const float* fc_b   = (const float*)d_in[12];
    float* out = (float*)d_out;

    unsigned short* h1 = (unsigned short*)d_ws;                    // bf16, 67 MiB
    float* out2 = (float*)((char*)d_ws + (size_t)BB*TT*64*2);      // f32, 134 MiB

    gru_l0<<<128, 64, 0, stream>>>(x, w_ih0, w_hh0, b_ih0, b_hh0, h1);
    gru_l1<<<128, 64, 0, stream>>>(h1, w_ih1, w_hh1, b_ih1, b_hh1, out2);
    attn_fc<<<BB, 256, 0, stream>>>(out2, attn_w, attn_b, fc_w, fc_b, out);
}